// Round 13
// baseline (58.608 us; speedup 1.0000x reference)
//
#include <hip/hip_runtime.h>
#include <hip/hip_fp16.h>

// Depthwise 3D Gaussian conv (1,3,160,160,160) fp32, K=25, radius=12.
// Separable. Round 13: fused W+H per (c,d)-plane half at 16 waves/CU
// (the 4 prior fusion failures all ran <=10 waves/CU):
//   block = 512 thr, LDS X[104][198]f16 + WB[104][170]f16 = 76.5KB -> 2/CU
//   stage: coalesced row-contiguous float4 (no scatter, no strides)
//   W phase: 832 tasks, 20 outputs each, scalar window from X
//   H phase: 640 tasks, 10 float2 outputs each, pk window from WB
//   weights: g[t]=g[24-t] symmetry -> 13 regs, VGPR fits the 128 cap.
// D pass unchanged (r11 full-w tile). Traffic 196 -> ~170 MB, 3 -> 2 launches.

#define NV 160
constexpr int KS    = 25;
constexpr int RAD   = 12;
constexpr int PLANE = NV * NV;        // 25600
constexpr int VOL   = NV * NV * NV;   // 4,096,000
constexpr int TOT   = 3 * VOL;        // 12,288,000

// fused W+H geometry
constexpr int FH  = 80;               // output h rows per block
constexpr int FR  = 104;              // staged rows (FH + 2*RAD)
constexpr int XP  = 198;              // X pitch (halfs; 99 dwords, odd)
constexpr int WPT = 170;              // WB pitch (halfs; 85 dwords, odd)

// conv_d geometry (r11)
constexpr int HC2   = 80;
constexpr int TR    = 104;
constexpr int TP2   = 84;             // half2 pitch
constexpr int NTASK = TR * 20;
constexpr int OPT   = 10;
constexpr int WIN   = OPT + KS - 1;   // 34

#define GW(t)  g[(t) < 13 ? (t) : 24 - (t)]
#define GW2(t) g2[(t) < 13 ? (t) : 24 - (t)]

__device__ __forceinline__ void pk(float2& a, float2 g, float2 v) {
    asm("v_pk_fma_f32 %0, %1, %2, %0" : "+v"(a) : "v"(g), "v"(v));
}

// Recover unique half of g1 (g1[t]=g1[24-t]): g1[t] = g3[t,12,12]/cbrt(g3[12,12,12])^2.
__device__ __forceinline__ void load_g13(const float* __restrict__ k3, float* g) {
    float c   = k3[12 * 625 + 312];
    float g12 = cbrtf(c);
    float inv = 1.0f / (g12 * g12);
#pragma unroll
    for (int t = 0; t < 13; ++t) g[t] = k3[t * 625 + 312] * inv;
}

// ---------------- fused W+H: f32 in -> f16 out ----------------
__global__ __launch_bounds__(512, 4) void fused_wh(const float* __restrict__ in,
                                                   __half* __restrict__ out,
                                                   const float* __restrict__ k3) {
    __shared__ __half X[FR][XP];             // 104*198*2 = 41184 B
    __shared__ __half WB[FR][WPT];           // 104*170*2 = 35360 B
    float g[13];
    load_g13(k3, g);

    int tid = threadIdx.x;
    int b   = blockIdx.x;
    int hh  = b & 1;
    int cd  = b >> 1;                  // c*160 + d
    int h0  = hh * FH;
    const float* base = in + (size_t)cd * PLANE;

    // zero the w-halo columns of X (cols 0..11 and 172..183)
    const __half2 Z2 = __float22half2_rn(make_float2(0.f, 0.f));
    for (int z = tid; z < FR * 12; z += 512) {
        int r = z / 12, u = z % 12;
        int col = (u < 6) ? 2 * u : 172 + 2 * (u - 6);
        *(__half2*)&X[r][col] = Z2;
    }
    // stage interior: 104 rows x 40 float4 tasks, row-contiguous coalesced
#pragma unroll
    for (int it = 0; it < 9; ++it) {
        int task = it * 512 + tid;
        if (task < FR * 40) {
            int r = task / 40, q = task % 40;
            int hg = h0 - RAD + r;
            float4 f = make_float4(0.f, 0.f, 0.f, 0.f);
            if (hg >= 0 && hg < NV)
                f = *(const float4*)(base + hg * NV + 4 * q);
            *(__half2*)&X[r][12 + 4 * q]     = __float22half2_rn(make_float2(f.x, f.y));
            *(__half2*)&X[r][12 + 4 * q + 2] = __float22half2_rn(make_float2(f.z, f.w));
        }
    }
    __syncthreads();

    // ---- W phase: 832 tasks = (row r 0..103) x (chunk cc 0..7 of 20 w) ----
#pragma unroll
    for (int it2 = 0; it2 < 2; ++it2) {
        int task = it2 * 512 + tid;
        if (task < FR * 8) {
            int cc = task & 7, r = task >> 3;
            float acc[20];
#pragma unroll
            for (int j = 0; j < 20; ++j) acc[j] = 0.f;
#pragma unroll
            for (int s = 0; s < 44; ++s) {
                float v = __half2float(X[r][20 * cc + s]);
#pragma unroll
                for (int j = 0; j < 20; ++j) {
                    int t = s - j;
                    if (t >= 0 && t < KS) acc[j] = fmaf(GW(t), v, acc[j]);
                }
            }
#pragma unroll
            for (int j = 0; j < 10; ++j)
                *(__half2*)&WB[r][20 * cc + 2 * j] =
                    __float22half2_rn(make_float2(acc[2 * j], acc[2 * j + 1]));
        }
    }
    __syncthreads();

    // ---- H phase: 640 tasks = (wp 0..79) x (chunk hc 0..7 of 10 h) ----
    float2 g2[13];
#pragma unroll
    for (int t = 0; t < 13; ++t) g2[t] = make_float2(g[t], g[t]);
#pragma unroll
    for (int it2 = 0; it2 < 2; ++it2) {
        int task = it2 * 512 + tid;
        if (task < 640) {
            int wp = task % 80, hc = task / 80;
            int hb = hc * 10;
            float2 acc[10];
#pragma unroll
            for (int j = 0; j < 10; ++j) acc[j] = make_float2(0.f, 0.f);
#pragma unroll
            for (int s = 0; s < 34; ++s) {
                float2 v = __half22float2(*(__half2*)&WB[hb + s][2 * wp]);
#pragma unroll
                for (int j = 0; j < 10; ++j) {
                    int t = s - j;
                    if (t >= 0 && t < KS) pk(acc[j], GW2(t), v);
                }
            }
            __half* op = out + (size_t)cd * PLANE + (size_t)(h0 + hb) * NV + 2 * wp;
#pragma unroll
            for (int j = 0; j < 10; ++j)
                *(__half2*)(op + j * NV) = __float22half2_rn(acc[j]);
        }
    }
}

// ---------------- D pass: f16 in -> f32 out (r11, proven) ----------------
__global__ __launch_bounds__(320) void conv_d(const __half* __restrict__ in,
                                              float* __restrict__ out,
                                              const float* __restrict__ k3) {
    __shared__ __half2 T[TR][TP2];           // 34944 B
    float g[13];
    load_g13(k3, g);
    float2 g2[13];
#pragma unroll
    for (int t = 0; t < 13; ++t) g2[t] = make_float2(g[t], g[t]);

    int tid = threadIdx.x;
    int b   = blockIdx.x;
    int dh  = b & 1;
    int ch  = b >> 1;              // c*160 + h
    int c   = ch / NV, h = ch % NV;
    int d0  = dh * HC2;
    const __half* base = in + (size_t)c * VOL + h * NV;

#pragma unroll
    for (int it = 0; it < 7; ++it) {
        int task = it * 320 + tid;
        if (task < NTASK) {
            int r = task / 20, k = task % 20;
            int dg = d0 - RAD + r;
            uint4 v = make_uint4(0u, 0u, 0u, 0u);
            if (dg >= 0 && dg < NV)
                v = *(const uint4*)(base + (size_t)dg * PLANE + 8 * k);
            *(uint4*)(&T[r][4 * k]) = v;
        }
    }
    __syncthreads();

    int wp = tid % 80, oc = tid / 80;
#pragma unroll
    for (int hv = 0; hv < 2; ++hv) {
        int rb = (oc + 4 * hv) * OPT;        // 0..70
        float2 acc[OPT];
#pragma unroll
        for (int j = 0; j < OPT; ++j) acc[j] = make_float2(0.f, 0.f);
#pragma unroll
        for (int it = 0; it < WIN; ++it) {
            float2 v = __half22float2(T[rb + it][wp]);
#pragma unroll
            for (int j = 0; j < OPT; ++j) {
                int t = it - j;
                if (t >= 0 && t < KS) pk(acc[j], GW2(t), v);
            }
        }
        float* op = out + (size_t)c * VOL + h * NV + 2 * wp;
#pragma unroll
        for (int j = 0; j < OPT; ++j)
            *(float2*)(op + (size_t)(d0 + rb + j) * PLANE) = acc[j];
    }
}

// Fallback (only if ws too small): direct 25^3-tap depthwise conv.
__global__ __launch_bounds__(256) void conv3d_direct(const float* __restrict__ x,
                                                     const float* __restrict__ k3,
                                                     float* __restrict__ out) {
    int idx = blockIdx.x * 256 + threadIdx.x;
    if (idx >= TOT) return;
    int w = idx % NV;
    int t = idx / NV;
    int h = t % NV; t /= NV;
    int d = t % NV;
    int c = t / NV;
    const float* kc = k3 + c * (KS * KS * KS);
    float acc = 0.f;
    for (int i = 0; i < KS; ++i) {
        int dd = d + i - RAD;
        if (dd < 0 || dd >= NV) continue;
        for (int j = 0; j < KS; ++j) {
            int hh = h + j - RAD;
            if (hh < 0 || hh >= NV) continue;
            const float* xr = x + (c * NV + dd) * NV * NV + hh * NV + (w - RAD);
            const float* kr = kc + (i * KS + j) * KS;
            int k0 = (RAD - w) > 0 ? (RAD - w) : 0;
            int k1 = (NV + RAD - w) < KS ? (NV + RAD - w) : KS;
            for (int k = k0; k < k1; ++k) acc += kr[k] * xr[k];
        }
    }
    out[idx] = acc;
}

extern "C" void kernel_launch(void* const* d_in, const int* in_sizes, int n_in,
                              void* d_out, int out_size, void* d_ws, size_t ws_size,
                              hipStream_t stream) {
    const float* x  = (const float*)d_in[0];
    const float* k3 = (const float*)d_in[1];
    float* out = (float*)d_out;

    if (ws_size >= (size_t)TOT * sizeof(__half)) {
        __half* tmpA = (__half*)d_ws;
        fused_wh<<<960, 512, 0, stream>>>(x, tmpA, k3);   // x -> tmpA (W+H, f16)
        conv_d<<<960, 320, 0, stream>>>(tmpA, out, k3);   // tmpA -> out (D, f32)
    } else {
        conv3d_direct<<<(TOT + 255) / 256, 256, 0, stream>>>(x, k3, out);
    }
}